// Round 14
// baseline (406.311 us; speedup 1.0000x reference)
//
#include <hip/hip_runtime.h>
#include <hip/hip_fp16.h>

// Problem constants (match reference setup_inputs()).
constexpr int Nn  = 200000;   // nodes
constexpr int Ne  = 3200000;  // edges
constexpr int Ng  = 8192;     // graphs
constexpr int FIN = 28;       // one-hot feature dim
constexpr int DE  = 50;       // embed dim
constexpr int HD  = 16;       // hidden
constexpr int CD  = 2;        // classes

// counting-sort geometry
constexpr int NBIN   = (Nn + 255) >> 8;        // 782 bins of 256 nodes
constexpr int NBLK   = 512;                    // pass-1 blocks
constexpr int CH     = Ne / NBLK;              // 6250 edges per pass-1 block (exact)
constexpr int CSTR   = 800;                    // count-matrix row stride (ints)
constexpr int LDSCAP = 4608;                   // bin cap (mean 4096, +8 sigma)

__device__ __forceinline__ float dec_ea(unsigned u) {
  return ((float)(u & 16383u) + 0.5f) * (1.0f / 16384.0f);
}

// fp8 = e5m2 via fp16 truncation (decode: shift to high byte; encode: RTN on bit7).
__device__ __forceinline__ float2 dec8(unsigned short u) {
  __half lo = __ushort_as_half((unsigned short)((u & 0x00ffu) << 8));
  __half hi = __ushort_as_half((unsigned short)(u & 0xff00u));
  return make_float2(__half2float(lo), __half2float(hi));
}
__device__ __forceinline__ unsigned char enc8(float f) {
  unsigned short b = __half_as_ushort(__float2half(f));
  return (unsigned char)((unsigned short)(b + 0x0080u) >> 8);
}

static inline int nblocks(long long n, int bs = 256, int cap = 16384) {
  long long b = (n + bs - 1) / bs;
  return (int)(b < cap ? b : cap);
}

// pass 1a: per-block histogram by 256-node bin (blocks 0..NBLK-1);
// block NBLK computes EW1 = emb @ W1 (fused to save a launch).
__global__ __launch_bounds__(256) void k_count(const int* __restrict__ col,
                                               int* __restrict__ counts,
                                               const float* __restrict__ emb,
                                               const float* __restrict__ W1,
                                               float* __restrict__ EW1) {
  if (blockIdx.x == NBLK) {
    int t = threadIdx.x;
    for (int u = t; u < FIN * HD; u += 256) {
      int i = u / HD, k = u % HD;
      float s = 0.0f;
      for (int j = 0; j < DE; ++j) s += emb[i * DE + j] * W1[j * HD + k];
      EW1[u] = s;
    }
    return;
  }
  __shared__ int c[NBIN];
  for (int i = threadIdx.x; i < NBIN; i += 256) c[i] = 0;
  __syncthreads();
  int lo = blockIdx.x * CH;
  for (int i = threadIdx.x; i < CH; i += 256) atomicAdd(&c[col[lo + i] >> 8], 1);
  __syncthreads();
  for (int i = threadIdx.x; i < NBIN; i += 256) counts[blockIdx.x * CSTR + i] = c[i];
}

// argmax(x) with COALESCED reads: stage 256 nodes x 112B into LDS via float4,
// then per-thread argmax from LDS. Fixes the 28-txn/node strided read pattern.
__global__ __launch_bounds__(256) void k_argmax(const float* __restrict__ x,
                                                unsigned char* __restrict__ arg) {
  __shared__ float xs[256 * FIN];   // 28 KB
  int b = blockIdx.x, t = threadIdx.x;
  int base = b << 8;                 // first node of this block
  int nval = min(256, Nn - base) * FIN;
  const float4* x4 = (const float4*)(x + (size_t)base * FIN);
  float4* s4 = (float4*)xs;
  int n4 = nval >> 2;                // FIN=28 -> nval divisible by 4
  for (int i = t; i < n4; i += 256) s4[i] = x4[i];
  __syncthreads();
  int node = base + t;
  if (node >= Nn) return;
  const float* xp = xs + t * FIN;
  int a = 0; float best = xp[0];
#pragma unroll
  for (int j = 1; j < FIN; ++j) { float v = xp[j]; if (v > best) { best = v; a = j; } }
  arg[node] = (unsigned char)a;
}

// pass 1b: per bin, exclusive scan over the 512 blocks (in place) + column total
__global__ __launch_bounds__(512) void k_scan1b(int* __restrict__ counts,
                                                int* __restrict__ colTotal) {
  __shared__ int s[NBLK];
  int bin = blockIdx.x, t = threadIdx.x;
  int v = counts[t * CSTR + bin];
  s[t] = v;
  __syncthreads();
  for (int d = 1; d < NBLK; d <<= 1) {
    int x = (t >= d) ? s[t - d] : 0;
    __syncthreads();
    s[t] += x;
    __syncthreads();
  }
  counts[t * CSTR + bin] = s[t] - v;   // exclusive prefix within bin
  if (t == NBLK - 1) colTotal[bin] = s[t];
}

// pass 1c: exclusive scan of bin totals -> binBase[0..NBIN]; start[Nn]=Ne;
// also zero sums/cnts (fused k_zero).
__global__ __launch_bounds__(1024) void k_scanBins(const int* __restrict__ colTotal,
                                                   int* __restrict__ binBase,
                                                   int* __restrict__ start,
                                                   float* __restrict__ zeroreg,
                                                   int nzero) {
  for (int i = threadIdx.x; i < nzero; i += 1024) zeroreg[i] = 0.0f;
  __shared__ int s[1024];
  int t = threadIdx.x;
  int v = (t < NBIN) ? colTotal[t] : 0;
  s[t] = v;
  __syncthreads();
  for (int d = 1; d < 1024; d <<= 1) {
    int x = (t >= d) ? s[t - d] : 0;
    __syncthreads();
    s[t] += x;
    __syncthreads();
  }
  if (t < NBIN) binBase[t] = s[t] - v;
  if (t == NBIN - 1) { binBase[NBIN] = s[t]; start[Nn] = s[t]; }  // both = Ne
}

// pass 1d: place edges into bin regions. Local bin counts come from adjacent
// counts rows (diff) -- no re-histogram. LDS bin-sort, then linear LDS->global
// sweep: consecutive entries of one bin write consecutive global addresses.
__global__ __launch_bounds__(256) void k_place(const int* __restrict__ row,
                                               const int* __restrict__ col,
                                               const float* __restrict__ ea,
                                               const int* __restrict__ counts,
                                               const int* __restrict__ colTotal,
                                               const int* __restrict__ binBase,
                                               unsigned long long* __restrict__ staged) {
  __shared__ unsigned long long stage[CH];   // 50 KB
  __shared__ int lhist[NBIN];                // local count -> exclusive local base
  __shared__ int lcur[NBIN];
  __shared__ int gbase[NBIN];
  __shared__ int partial[256];
  int blk = blockIdx.x, t = threadIdx.x;
  int lo = blk * CH;
  for (int i = t; i < NBIN; i += 256) {
    int cur = counts[blk * CSTR + i];
    int nxt = (blk == NBLK - 1) ? colTotal[i] : counts[(blk + 1) * CSTR + i];
    lhist[i] = nxt - cur;   // this block's count for bin i
    lcur[i] = 0;
    gbase[i] = binBase[i] + cur;
  }
  __syncthreads();
  // exclusive scan of lhist (782 bins: 4 per thread + 256-wide scan)
  constexpr int CPT = (NBIN + 255) / 256;  // 4
  int b0 = t * CPT, s = 0;
#pragma unroll
  for (int j = 0; j < CPT; ++j) { int b = b0 + j; if (b < NBIN) s += lhist[b]; }
  partial[t] = s;
  __syncthreads();
  for (int d = 1; d < 256; d <<= 1) {
    int x = (t >= d) ? partial[t - d] : 0;
    __syncthreads();
    partial[t] += x;
    __syncthreads();
  }
  int run = partial[t] - s;  // exclusive
#pragma unroll
  for (int j = 0; j < CPT; ++j) {
    int b = b0 + j;
    if (b < NBIN) { int c = lhist[b]; lhist[b] = run; run += c; }
  }
  __syncthreads();
  // place into LDS staging at bin-sorted position
  for (int i = t; i < CH; i += 256) {
    int e = lo + i;
    int c = col[e], bin = c >> 8;
    unsigned q = (unsigned)__float2int_rd(ea[e] * 16384.0f);
    if (q > 16383u) q = 16383u;
    unsigned long long entry =
        ((unsigned long long)(unsigned)c << 32) | ((unsigned)row[e] << 14) | q;
    int pos = lhist[bin] + atomicAdd(&lcur[bin], 1);
    stage[pos] = entry;
  }
  __syncthreads();
  // linear LDS read -> run-coalesced global write
  for (int i = t; i < CH; i += 256) {
    unsigned long long entry = stage[i];
    int bin = (int)(entry >> 40);  // col>>8
    staged[gbase[bin] + (i - lhist[bin])] = entry;
  }
}

// pass 2 (+fused embed): per bin, sort staged edges by node (LDS count+scan+place),
// write exact CSR + start[]; then dinv from in-LDS sdeg, hws1 = fp8(EW1[arg]*dinv).
__global__ __launch_bounds__(256) void k_finemb(const int* __restrict__ binBase,
                                                const unsigned long long* __restrict__ staged,
                                                const unsigned char* __restrict__ arg,
                                                const float* __restrict__ EW1,
                                                unsigned* __restrict__ csr,
                                                int* __restrict__ start,
                                                float* __restrict__ dinv,
                                                unsigned char* __restrict__ hws1) {
  __shared__ int ncnt[256];
  __shared__ int noff[256];
  __shared__ int ncur[256];
  __shared__ float sdeg[256];
  __shared__ unsigned outb[LDSCAP];
  int b = blockIdx.x, t = threadIdx.x;
  int lo = binBase[b];
  int cnt = binBase[b + 1] - lo;
  if (cnt > LDSCAP) cnt = LDSCAP;  // 8-sigma safety, never expected
  ncnt[t] = 0; ncur[t] = 0; sdeg[t] = 0.0f;
  __syncthreads();
  for (int i = t; i < cnt; i += 256) {
    unsigned long long p = staged[lo + i];
    int cl = (int)((p >> 32) & 255u);
    atomicAdd(&ncnt[cl], 1);
    atomicAdd(&sdeg[cl], dec_ea((unsigned)p));
  }
  __syncthreads();
  int v = ncnt[t];
  noff[t] = v;
  __syncthreads();
  for (int d = 1; d < 256; d <<= 1) {
    int xsh = (t >= d) ? noff[t - d] : 0;
    __syncthreads();
    noff[t] += xsh;
    __syncthreads();
  }
  int excl = noff[t] - v;
  __syncthreads();
  noff[t] = excl;
  __syncthreads();
  for (int i = t; i < cnt; i += 256) {
    unsigned long long p = staged[lo + i];
    int cl = (int)((p >> 32) & 255u);
    int idx = noff[cl] + atomicAdd(&ncur[cl], 1);
    outb[idx] = (unsigned)p;  // row<<14 | ea_q
  }
  __syncthreads();
  for (int i = t; i < cnt; i += 256) csr[lo + i] = outb[i];
  int node = (b << 8) + t;
  if (node >= Nn) return;
  start[node] = lo + noff[t];
  float di = rsqrtf(sdeg[t] + 1.0f);
  dinv[node] = di;
  const float* ep = EW1 + (int)arg[node] * HD;
#pragma unroll
  for (int k = 0; k < HD; ++k) hws1[((size_t)node << 4) + k] = enc8(ep[k] * di);
}

// Fused conv, ONE WAVE PER NODE: 8 edge-slots x 8 lanes (lane = 2 fp8 feats).
// 3 BATCHED independent rounds (deg<=24, ~98%) issued before any wait. Grid-stride.
template <int OUTC>
__global__ __launch_bounds__(256) void k_conv(const int* __restrict__ start,
                                              const unsigned* __restrict__ csr,
                                              const unsigned short* __restrict__ f8,
                                              const float* __restrict__ dinv,
                                              const float* __restrict__ bias,
                                              const float* __restrict__ Wn,
                                              void* __restrict__ outw) {
  int lane = threadIdx.x & 63;
  int slot = lane >> 3;                          // 0..7 edge slot
  int p    = lane & 7;                           // feat pair: k = 2p, 2p+1
  int k    = lane & 15;
  int nstep = gridDim.x * 4;
  for (int n = blockIdx.x * 4 + (threadIdx.x >> 6); n < Nn; n += nstep) {
    int lo = start[n], hi = start[n + 1];
    int j0 = lo + slot;
    bool e0 = j0 < hi, e1 = j0 + 8 < hi, e2 = j0 + 16 < hi;
    // batched independent loads (invalid -> csr[0], weight forced 0)
    unsigned u0 = __builtin_nontemporal_load(csr + (e0 ? j0 : 0));
    unsigned u1 = __builtin_nontemporal_load(csr + (e1 ? j0 + 8 : 0));
    unsigned u2 = __builtin_nontemporal_load(csr + (e2 ? j0 + 16 : 0));
    float w0 = e0 ? dec_ea(u0) : 0.0f;
    float w1 = e1 ? dec_ea(u1) : 0.0f;
    float w2 = e2 ? dec_ea(u2) : 0.0f;
    float2 v0 = dec8(f8[((u0 >> 14) << 3) + p]);
    float2 v1 = dec8(f8[((u1 >> 14) << 3) + p]);
    float2 v2 = dec8(f8[((u2 >> 14) << 3) + p]);
    float ax = fmaf(v2.x, w2, fmaf(v1.x, w1, v0.x * w0));
    float ay = fmaf(v2.y, w2, fmaf(v1.y, w1, v0.y * w0));
    for (int j = j0 + 24; j < hi; j += 8) {   // rare tail (deg > 24)
      unsigned u = __builtin_nontemporal_load(csr + j);
      float w = dec_ea(u);
      float2 v = dec8(f8[((u >> 14) << 3) + p]);
      ax = fmaf(v.x, w, ax);
      ay = fmaf(v.y, w, ay);
    }
#pragma unroll
    for (int d = 8; d < 64; d <<= 1) {
      ax += __shfl_xor(ax, d, 64);
      ay += __shfl_xor(ay, d, 64);
    }
    float di = dinv[n];
    float2 self = dec8(f8[((size_t)n << 3) + p]);
    float h0 = fmaxf(di * (ax + self.x) + bias[2 * p + 0], 0.0f);
    float h1 = fmaxf(di * (ay + self.y) + bias[2 * p + 1], 0.0f);
    // matmul: lane k computes out[k]; h[2q],h[2q+1] broadcast from lane q
    float acc2 = 0.0f;
#pragma unroll
    for (int q = 0; q < 8; ++q) {
      float hj0 = __shfl(h0, q, 64);
      float hj1 = __shfl(h1, q, 64);
      acc2 = fmaf(hj0, Wn[(2 * q + 0) * OUTC + (OUTC == 16 ? k : (k & 1))], acc2);
      acc2 = fmaf(hj1, Wn[(2 * q + 1) * OUTC + (OUTC == 16 ? k : (k & 1))], acc2);
    }
    acc2 *= di;
    if (OUTC == 16) {
      if (lane < 16) ((unsigned char*)outw)[((size_t)n << 4) + k] = enc8(acc2);
    } else {
      if (lane < CD) ((__half*)outw)[(size_t)n * CD + k] = __float2half(acc2);
    }
  }
}

// conv3 epilogue (no relu) + mean-pool: 8 nodes x 8 edge-slots per wave,
// 3 batched rounds (deg<=24) + tail. h3 fp16 half2 (800 KB, L2-resident).
__global__ __launch_bounds__(256) void k_conv3pool(const int* __restrict__ start,
                                                   const unsigned* __restrict__ csr,
                                                   const __half* __restrict__ h3,
                                                   const float* __restrict__ dinv,
                                                   const float* __restrict__ b3,
                                                   const int* __restrict__ batch,
                                                   float* __restrict__ sums,
                                                   float* __restrict__ cnts) {
  const __half2* h2 = (const __half2*)h3;
  int lane = threadIdx.x & 63;
  int nsub = lane >> 3;   // 0..7 node within wave
  int slot = lane & 7;    // 0..7 edge slot
  int wid  = threadIdx.x >> 6;
  int nstep = gridDim.x * 32;
  for (int nb = (blockIdx.x * 4 + wid) * 8; nb < Nn; nb += nstep) {
    int n = nb + nsub;
    int nn = min(n, Nn - 1);
    int lo = start[nn], hi = start[nn + 1];
    int j0 = lo + slot;
    bool e0 = j0 < hi, e1 = j0 + 8 < hi, e2 = j0 + 16 < hi;
    unsigned u0 = __builtin_nontemporal_load(csr + (e0 ? j0 : 0));
    unsigned u1 = __builtin_nontemporal_load(csr + (e1 ? j0 + 8 : 0));
    unsigned u2 = __builtin_nontemporal_load(csr + (e2 ? j0 + 16 : 0));
    float w0 = e0 ? dec_ea(u0) : 0.0f;
    float w1 = e1 ? dec_ea(u1) : 0.0f;
    float w2 = e2 ? dec_ea(u2) : 0.0f;
    float2 v0 = __half22float2(h2[u0 >> 14]);
    float2 v1 = __half22float2(h2[u1 >> 14]);
    float2 v2 = __half22float2(h2[u2 >> 14]);
    float ax = fmaf(v2.x, w2, fmaf(v1.x, w1, v0.x * w0));
    float ay = fmaf(v2.y, w2, fmaf(v1.y, w1, v0.y * w0));
    for (int j = j0 + 24; j < hi; j += 8) {
      unsigned u = __builtin_nontemporal_load(csr + j);
      float w = dec_ea(u);
      float2 v = __half22float2(h2[u >> 14]);
      ax = fmaf(v.x, w, ax);
      ay = fmaf(v.y, w, ay);
    }
    ax += __shfl_xor(ax, 1, 64); ay += __shfl_xor(ay, 1, 64);
    ax += __shfl_xor(ax, 2, 64); ay += __shfl_xor(ay, 2, 64);
    ax += __shfl_xor(ax, 4, 64); ay += __shfl_xor(ay, 4, 64);
    if (slot == 0 && n < Nn) {
      float di = dinv[n];
      float2 self = __half22float2(h2[n]);
      float a0 = di * (ax + self.x) + b3[0];
      float a1 = di * (ay + self.y) + b3[1];
      int g = batch[n];
      atomicAdd(&sums[2 * g + 0], a0);
      atomicAdd(&sums[2 * g + 1], a1);
      atomicAdd(&cnts[g], 1.0f);
    }
  }
}

__global__ void k_softmax(const float* __restrict__ sums, const float* __restrict__ cnts,
                          float* __restrict__ out, int g) {
  int stride = gridDim.x * blockDim.x;
  for (int i = blockIdx.x * blockDim.x + threadIdx.x; i < g; i += stride) {
    float cnt = fmaxf(cnts[i], 1.0f);
    float c0 = sums[i * 2 + 0] / cnt;
    float c1 = sums[i * 2 + 1] / cnt;
    float m = fmaxf(c0, c1);
    float e0 = __expf(c0 - m), e1 = __expf(c1 - m);
    float inv = 1.0f / (e0 + e1);
    out[i * 2 + 0] = e0 * inv;
    out[i * 2 + 1] = e1 * inv;
  }
}

extern "C" void kernel_launch(void* const* d_in, const int* in_sizes, int n_in,
                              void* d_out, int out_size, void* d_ws, size_t ws_size,
                              hipStream_t stream) {
  const float* x   = (const float*)d_in[0];
  const int*   row = (const int*)d_in[1];
  const int*   col = (const int*)d_in[2];
  const float* ea  = (const float*)d_in[3];
  const int*   bat = (const int*)d_in[4];
  const float* emb = (const float*)d_in[5];
  const float* W1  = (const float*)d_in[6];
  const float* b1  = (const float*)d_in[7];
  const float* W2  = (const float*)d_in[8];
  const float* b2  = (const float*)d_in[9];
  const float* W3  = (const float*)d_in[10];
  const float* b3  = (const float*)d_in[11];
  float* out = (float*)d_out;

  // workspace layout (floats); chunk sizes keep 8B alignment
  float* ws = (float*)d_ws;
  size_t o = 0;
  float* sums    = ws + o; o += (size_t)Ng * CD;       // zeroed in k_scanBins
  float* cnts    = ws + o; o += Ng;                    // zeroed in k_scanBins
  float* dinv    = ws + o; o += Nn;
  float* EW1     = ws + o; o += FIN * HD + 16;
  int*   counts  = (int*)(ws + o); o += (size_t)NBLK * CSTR;
  int*   colTot  = (int*)(ws + o); o += CSTR;
  int*   binBase = (int*)(ws + o); o += 1024;
  int*   startp  = (int*)(ws + o); o += Nn + 16;
  unsigned char* argb = (unsigned char*)(ws + o); o += Nn / 4 + 16;  // 1B/node
  unsigned long long* staged = (unsigned long long*)(ws + o); o += (size_t)Ne * 2;
  unsigned* csr  = (unsigned*)(ws + o); o += (size_t)Ne;
  unsigned char* hws1 = (unsigned char*)(ws + o); o += (size_t)Nn * HD / 4;  // fp8
  unsigned char* hws2 = (unsigned char*)(ws + o); o += (size_t)Nn * HD / 4;  // fp8
  __half* hw3s   = (__half*)(ws + o); o += (size_t)Nn * CD / 2;
  (void)ws_size; (void)n_in; (void)in_sizes; (void)out_size;

  // counting-sort CSR build + coalesced argmax
  k_count<<<NBLK + 1, 256, 0, stream>>>(col, counts, emb, W1, EW1);
  k_argmax<<<NBIN, 256, 0, stream>>>(x, argb);
  k_scan1b<<<NBIN, NBLK, 0, stream>>>(counts, colTot);
  k_scanBins<<<1, 1024, 0, stream>>>(colTot, binBase, startp, sums, Ng * (CD + 1));
  k_place<<<NBLK, 256, 0, stream>>>(row, col, ea, counts, colTot, binBase, staged);
  k_finemb<<<NBIN, 256, 0, stream>>>(binBase, staged, argb, EW1, csr, startp, dinv, hws1);

  // wave-per-node convs; batched independent gathers
  k_conv<16><<<nblocks((long long)Nn * 64), 256, 0, stream>>>(
      startp, csr, (const unsigned short*)hws1, dinv, b1, W2, hws2);
  k_conv<2><<<nblocks((long long)Nn * 64), 256, 0, stream>>>(
      startp, csr, (const unsigned short*)hws2, dinv, b2, W3, hw3s);

  k_conv3pool<<<nblocks((long long)Nn * 8), 256, 0, stream>>>(
      startp, csr, hw3s, dinv, b3, bat, sums, cnts);

  k_softmax<<<nblocks(Ng), 256, 0, stream>>>(sums, cnts, out, Ng);
}

// Round 15
// 373.374 us; speedup vs baseline: 1.0882x; 1.0882x over previous
//
#include <hip/hip_runtime.h>
#include <hip/hip_fp16.h>

// Problem constants (match reference setup_inputs()).
constexpr int Nn  = 200000;   // nodes
constexpr int Ne  = 3200000;  // edges
constexpr int Ng  = 8192;     // graphs
constexpr int FIN = 28;       // one-hot feature dim
constexpr int DE  = 50;       // embed dim
constexpr int HD  = 16;       // hidden
constexpr int CD  = 2;        // classes

// one-pass counting-sort geometry
constexpr int NBIN = (Nn + 255) >> 8;          // 782 bins of 256 nodes
constexpr int NBLK = 512;                      // place blocks
constexpr int CH   = Ne / NBLK;                // 6250 edges per place block (exact)
constexpr int CAPB = 4608;                     // fixed bin region capacity (mean 4096, +8 sigma)

__device__ __forceinline__ float dec_ea(unsigned u) {
  return ((float)(u & 16383u) + 0.5f) * (1.0f / 16384.0f);
}

// fp8 = e5m2 via fp16 truncation (decode: shift to high byte; encode: RTN on bit7).
__device__ __forceinline__ float2 dec8(unsigned short u) {
  __half lo = __ushort_as_half((unsigned short)((u & 0x00ffu) << 8));
  __half hi = __ushort_as_half((unsigned short)(u & 0xff00u));
  return make_float2(__half2float(lo), __half2float(hi));
}
__device__ __forceinline__ unsigned char enc8(float f) {
  unsigned short b = __half_as_ushort(__float2half(f));
  return (unsigned char)((unsigned short)(b + 0x0080u) >> 8);
}

static inline int nblocks(long long n, int bs = 256, int cap = 16384) {
  long long b = (n + bs - 1) / bs;
  return (int)(b < cap ? b : cap);
}

// pre-pass: blocks 0..NBIN-1 = coalesced argmax(x) via LDS staging;
// block NBIN = EW1 = emb@W1; block NBIN+1 = zero (sums|cnts|gcur region).
__global__ __launch_bounds__(256) void k_pre(const float* __restrict__ x,
                                             unsigned char* __restrict__ arg,
                                             const float* __restrict__ emb,
                                             const float* __restrict__ W1,
                                             float* __restrict__ EW1,
                                             float* __restrict__ zreg, int nz) {
  int b = blockIdx.x, t = threadIdx.x;
  if (b == NBIN) {
    for (int u = t; u < FIN * HD; u += 256) {
      int i = u / HD, k = u % HD;
      float s = 0.0f;
      for (int j = 0; j < DE; ++j) s += emb[i * DE + j] * W1[j * HD + k];
      EW1[u] = s;
    }
    return;
  }
  if (b == NBIN + 1) {
    for (int i = t; i < nz; i += 256) zreg[i] = 0.0f;
    return;
  }
  __shared__ float xs[256 * FIN];   // 28 KB
  int base = b << 8;
  int nval = min(256, Nn - base) * FIN;
  const float4* x4 = (const float4*)(x + (size_t)base * FIN);
  float4* s4 = (float4*)xs;
  for (int i = t; i < (nval >> 2); i += 256) s4[i] = x4[i];
  __syncthreads();
  int node = base + t;
  if (node >= Nn) return;
  const float* xp = xs + t * FIN;
  int a = 0; float best = xp[0];
#pragma unroll
  for (int j = 1; j < FIN; ++j) { float v = xp[j]; if (v > best) { best = v; a = j; } }
  arg[node] = (unsigned char)a;
}

// ONE-PASS place: per-block LDS histogram -> local scan -> per-bin global
// atomic reservation in fixed-capacity regions -> LDS bin-sort -> coalesced
// global write. staged entry: hi32 = col, lo32 = row(18b)<<14 | ea_q(14b).
__global__ __launch_bounds__(256) void k_place1(const int* __restrict__ row,
                                                const int* __restrict__ col,
                                                const float* __restrict__ ea,
                                                int* __restrict__ gcur,
                                                unsigned long long* __restrict__ staged) {
  __shared__ unsigned long long stage[CH];   // 50 KB
  __shared__ int lhist[NBIN];                // count -> exclusive local base
  __shared__ int lcur[NBIN];
  __shared__ int gbase[NBIN];                // reserved offset within bin region
  __shared__ int partial[256];
  int blk = blockIdx.x, t = threadIdx.x;
  int lo = blk * CH;
  for (int i = t; i < NBIN; i += 256) { lhist[i] = 0; lcur[i] = 0; }
  __syncthreads();
  for (int i = t; i < CH; i += 256) atomicAdd(&lhist[col[lo + i] >> 8], 1);
  __syncthreads();
  // exclusive scan of lhist (4 bins per thread + 256-wide scan); reserve global
  constexpr int CPT = (NBIN + 255) / 256;  // 4
  int b0 = t * CPT, s = 0;
  int cnt_[CPT];
#pragma unroll
  for (int j = 0; j < CPT; ++j) {
    int b = b0 + j;
    cnt_[j] = (b < NBIN) ? lhist[b] : 0;
    s += cnt_[j];
  }
  partial[t] = s;
  __syncthreads();
  for (int d = 1; d < 256; d <<= 1) {
    int v = (t >= d) ? partial[t - d] : 0;
    __syncthreads();
    partial[t] += v;
    __syncthreads();
  }
  int run = partial[t] - s;  // exclusive
#pragma unroll
  for (int j = 0; j < CPT; ++j) {
    int b = b0 + j;
    if (b < NBIN) {
      lhist[b] = run; run += cnt_[j];
      if (cnt_[j] > 0) gbase[b] = atomicAdd(&gcur[b], cnt_[j]);
    }
  }
  __syncthreads();
  // place into LDS staging at bin-sorted position
  for (int i = t; i < CH; i += 256) {
    int e = lo + i;
    int c = col[e], bin = c >> 8;
    unsigned q = (unsigned)__float2int_rd(ea[e] * 16384.0f);
    if (q > 16383u) q = 16383u;
    unsigned long long entry =
        ((unsigned long long)(unsigned)c << 32) | ((unsigned)row[e] << 14) | q;
    int pos = lhist[bin] + atomicAdd(&lcur[bin], 1);
    stage[pos] = entry;
  }
  __syncthreads();
  // linear LDS read -> run-coalesced global write into fixed bin regions
  for (int i = t; i < CH; i += 256) {
    unsigned long long entry = stage[i];
    int bin = (int)(entry >> 40);  // col>>8
    int rel = gbase[bin] + (i - lhist[bin]);
    if (rel < CAPB) staged[(size_t)bin * CAPB + rel] = entry;
  }
}

// fine sort per bin (+fused embed): LDS count+scan+place -> padded CSR,
// start/deg per node, weighted degree (atomic-free, from own sorted range),
// dinv, hws1 = fp8(EW1[arg]*dinv).
__global__ __launch_bounds__(256) void k_fine2(const int* __restrict__ gcur,
                                               const unsigned long long* __restrict__ staged,
                                               const unsigned char* __restrict__ arg,
                                               const float* __restrict__ EW1,
                                               unsigned* __restrict__ csr,
                                               int* __restrict__ startp,
                                               unsigned short* __restrict__ degw,
                                               float* __restrict__ dinv,
                                               unsigned char* __restrict__ hws1) {
  __shared__ int ncnt[256];
  __shared__ int noff[256];
  __shared__ int ncur[256];
  __shared__ unsigned outb[CAPB];   // 18 KB
  int b = blockIdx.x, t = threadIdx.x;
  int lo = b * CAPB;
  int cnt = min(gcur[b], CAPB);
  ncnt[t] = 0; ncur[t] = 0;
  __syncthreads();
  for (int i = t; i < cnt; i += 256)
    atomicAdd(&ncnt[(int)((staged[lo + i] >> 32) & 255u)], 1);
  __syncthreads();
  int v = ncnt[t];
  noff[t] = v;
  __syncthreads();
  for (int d = 1; d < 256; d <<= 1) {
    int xsh = (t >= d) ? noff[t - d] : 0;
    __syncthreads();
    noff[t] += xsh;
    __syncthreads();
  }
  int excl = noff[t] - v;
  __syncthreads();
  noff[t] = excl;
  __syncthreads();
  for (int i = t; i < cnt; i += 256) {
    unsigned long long p = staged[lo + i];
    int cl = (int)((p >> 32) & 255u);
    outb[noff[cl] + atomicAdd(&ncur[cl], 1)] = (unsigned)p;  // row<<14 | ea_q
  }
  __syncthreads();
  for (int i = t; i < cnt; i += 256) csr[lo + i] = outb[i];
  int node = (b << 8) + t;
  if (node >= Nn) return;
  int base = noff[t], c = ncnt[t];
  float s = 0.0f;
  for (int j = 0; j < c; ++j) s += dec_ea(outb[base + j]);  // atomic-free degree
  startp[node] = lo + base;
  degw[node] = (unsigned short)c;
  float di = rsqrtf(s + 1.0f);
  dinv[node] = di;
  const float* ep = EW1 + (int)arg[node] * HD;
#pragma unroll
  for (int k = 0; k < HD; ++k) hws1[((size_t)node << 4) + k] = enc8(ep[k] * di);
}

// Fused conv, ONE WAVE PER NODE: 8 edge-slots x 8 lanes (lane = 2 fp8 feats).
// 3 BATCHED independent rounds (deg<=24, ~98%) issued before any wait. Grid-stride.
template <int OUTC>
__global__ __launch_bounds__(256) void k_conv(const int* __restrict__ start,
                                              const unsigned short* __restrict__ degw,
                                              const unsigned* __restrict__ csr,
                                              const unsigned short* __restrict__ f8,
                                              const float* __restrict__ dinv,
                                              const float* __restrict__ bias,
                                              const float* __restrict__ Wn,
                                              void* __restrict__ outw) {
  int lane = threadIdx.x & 63;
  int slot = lane >> 3;                          // 0..7 edge slot
  int p    = lane & 7;                           // feat pair: k = 2p, 2p+1
  int k    = lane & 15;
  int nstep = gridDim.x * 4;
  for (int n = blockIdx.x * 4 + (threadIdx.x >> 6); n < Nn; n += nstep) {
    int lo = start[n], hi = lo + degw[n];
    int j0 = lo + slot;
    bool e0 = j0 < hi, e1 = j0 + 8 < hi, e2 = j0 + 16 < hi;
    // batched independent loads (invalid -> csr[0], weight forced 0)
    unsigned u0 = __builtin_nontemporal_load(csr + (e0 ? j0 : 0));
    unsigned u1 = __builtin_nontemporal_load(csr + (e1 ? j0 + 8 : 0));
    unsigned u2 = __builtin_nontemporal_load(csr + (e2 ? j0 + 16 : 0));
    float w0 = e0 ? dec_ea(u0) : 0.0f;
    float w1 = e1 ? dec_ea(u1) : 0.0f;
    float w2 = e2 ? dec_ea(u2) : 0.0f;
    float2 v0 = dec8(f8[((u0 >> 14) << 3) + p]);
    float2 v1 = dec8(f8[((u1 >> 14) << 3) + p]);
    float2 v2 = dec8(f8[((u2 >> 14) << 3) + p]);
    float ax = fmaf(v2.x, w2, fmaf(v1.x, w1, v0.x * w0));
    float ay = fmaf(v2.y, w2, fmaf(v1.y, w1, v0.y * w0));
    for (int j = j0 + 24; j < hi; j += 8) {   // rare tail (deg > 24)
      unsigned u = __builtin_nontemporal_load(csr + j);
      float w = dec_ea(u);
      float2 v = dec8(f8[((u >> 14) << 3) + p]);
      ax = fmaf(v.x, w, ax);
      ay = fmaf(v.y, w, ay);
    }
#pragma unroll
    for (int d = 8; d < 64; d <<= 1) {
      ax += __shfl_xor(ax, d, 64);
      ay += __shfl_xor(ay, d, 64);
    }
    float di = dinv[n];
    float2 self = dec8(f8[((size_t)n << 3) + p]);
    float h0 = fmaxf(di * (ax + self.x) + bias[2 * p + 0], 0.0f);
    float h1 = fmaxf(di * (ay + self.y) + bias[2 * p + 1], 0.0f);
    // matmul: lane k computes out[k]; h[2q],h[2q+1] broadcast from lane q
    float acc2 = 0.0f;
#pragma unroll
    for (int q = 0; q < 8; ++q) {
      float hj0 = __shfl(h0, q, 64);
      float hj1 = __shfl(h1, q, 64);
      acc2 = fmaf(hj0, Wn[(2 * q + 0) * OUTC + (OUTC == 16 ? k : (k & 1))], acc2);
      acc2 = fmaf(hj1, Wn[(2 * q + 1) * OUTC + (OUTC == 16 ? k : (k & 1))], acc2);
    }
    acc2 *= di;
    if (OUTC == 16) {
      if (lane < 16) ((unsigned char*)outw)[((size_t)n << 4) + k] = enc8(acc2);
    } else {
      if (lane < CD) ((__half*)outw)[(size_t)n * CD + k] = __float2half(acc2);
    }
  }
}

// conv3 epilogue (no relu) + mean-pool: 8 nodes x 8 edge-slots per wave.
// batch[] is sorted -> wave's 8 nodes usually share one graph: detect run
// uniformity via shfl_xor min/max and emit 3 atomics instead of 24.
__global__ __launch_bounds__(256) void k_conv3pool(const int* __restrict__ start,
                                                   const unsigned short* __restrict__ degw,
                                                   const unsigned* __restrict__ csr,
                                                   const __half* __restrict__ h3,
                                                   const float* __restrict__ dinv,
                                                   const float* __restrict__ b3,
                                                   const int* __restrict__ batch,
                                                   float* __restrict__ sums,
                                                   float* __restrict__ cnts) {
  const __half2* h2 = (const __half2*)h3;
  int lane = threadIdx.x & 63;
  int nsub = lane >> 3;   // 0..7 node within wave
  int slot = lane & 7;    // 0..7 edge slot
  int wid  = threadIdx.x >> 6;
  int nstep = gridDim.x * 32;
  for (int nb = (blockIdx.x * 4 + wid) * 8; nb < Nn; nb += nstep) {
    int n = nb + nsub;
    int nn = min(n, Nn - 1);
    int lo = start[nn], hi = lo + degw[nn];
    int j0 = lo + slot;
    bool e0 = j0 < hi, e1 = j0 + 8 < hi, e2 = j0 + 16 < hi;
    unsigned u0 = __builtin_nontemporal_load(csr + (e0 ? j0 : 0));
    unsigned u1 = __builtin_nontemporal_load(csr + (e1 ? j0 + 8 : 0));
    unsigned u2 = __builtin_nontemporal_load(csr + (e2 ? j0 + 16 : 0));
    float w0 = e0 ? dec_ea(u0) : 0.0f;
    float w1 = e1 ? dec_ea(u1) : 0.0f;
    float w2 = e2 ? dec_ea(u2) : 0.0f;
    float2 v0 = __half22float2(h2[u0 >> 14]);
    float2 v1 = __half22float2(h2[u1 >> 14]);
    float2 v2 = __half22float2(h2[u2 >> 14]);
    float ax = fmaf(v2.x, w2, fmaf(v1.x, w1, v0.x * w0));
    float ay = fmaf(v2.y, w2, fmaf(v1.y, w1, v0.y * w0));
    for (int j = j0 + 24; j < hi; j += 8) {
      unsigned u = __builtin_nontemporal_load(csr + j);
      float w = dec_ea(u);
      float2 v = __half22float2(h2[u >> 14]);
      ax = fmaf(v.x, w, ax);
      ay = fmaf(v.y, w, ay);
    }
    ax += __shfl_xor(ax, 1, 64); ay += __shfl_xor(ay, 1, 64);
    ax += __shfl_xor(ax, 2, 64); ay += __shfl_xor(ay, 2, 64);
    ax += __shfl_xor(ax, 4, 64); ay += __shfl_xor(ay, 4, 64);
    // slot-0 lanes (lane = nsub*8) now hold the full edge sum for node n
    bool valid = (n < Nn);
    float a0 = 0.0f, a1 = 0.0f;
    int g = 0;
    if (valid) {
      float di = dinv[n];
      float2 self = __half22float2(h2[n]);
      a0 = di * (ax + self.x) + b3[0];
      a1 = di * (ay + self.y) + b3[1];
      g = batch[n];
    }
    // run-uniformity among the 8 slot-0 lanes (xor dists 8/16/32 stay in-set)
    float aa0 = valid ? a0 : 0.0f, aa1 = valid ? a1 : 0.0f;
    float cc  = valid ? 1.0f : 0.0f;
    int gmx = valid ? g : -1;
    int gmn = valid ? g : 0x7fffffff;
#pragma unroll
    for (int d = 8; d < 64; d <<= 1) {
      aa0 += __shfl_xor(aa0, d, 64);
      aa1 += __shfl_xor(aa1, d, 64);
      cc  += __shfl_xor(cc, d, 64);
      gmx = max(gmx, __shfl_xor(gmx, d, 64));
      gmn = min(gmn, __shfl_xor(gmn, d, 64));
    }
    if (slot == 0) {
      if (gmn == gmx) {               // all valid nodes in wave share graph g
        if (nsub == 0 && valid) {
          atomicAdd(&sums[2 * g + 0], aa0);
          atomicAdd(&sums[2 * g + 1], aa1);
          atomicAdd(&cnts[g], cc);
        }
      } else if (valid) {
        atomicAdd(&sums[2 * g + 0], a0);
        atomicAdd(&sums[2 * g + 1], a1);
        atomicAdd(&cnts[g], 1.0f);
      }
    }
  }
}

__global__ void k_softmax(const float* __restrict__ sums, const float* __restrict__ cnts,
                          float* __restrict__ out, int g) {
  int stride = gridDim.x * blockDim.x;
  for (int i = blockIdx.x * blockDim.x + threadIdx.x; i < g; i += stride) {
    float cnt = fmaxf(cnts[i], 1.0f);
    float c0 = sums[i * 2 + 0] / cnt;
    float c1 = sums[i * 2 + 1] / cnt;
    float m = fmaxf(c0, c1);
    float e0 = __expf(c0 - m), e1 = __expf(c1 - m);
    float inv = 1.0f / (e0 + e1);
    out[i * 2 + 0] = e0 * inv;
    out[i * 2 + 1] = e1 * inv;
  }
}

extern "C" void kernel_launch(void* const* d_in, const int* in_sizes, int n_in,
                              void* d_out, int out_size, void* d_ws, size_t ws_size,
                              hipStream_t stream) {
  const float* x   = (const float*)d_in[0];
  const int*   row = (const int*)d_in[1];
  const int*   col = (const int*)d_in[2];
  const float* ea  = (const float*)d_in[3];
  const int*   bat = (const int*)d_in[4];
  const float* emb = (const float*)d_in[5];
  const float* W1  = (const float*)d_in[6];
  const float* b1  = (const float*)d_in[7];
  const float* W2  = (const float*)d_in[8];
  const float* b2  = (const float*)d_in[9];
  const float* W3  = (const float*)d_in[10];
  const float* b3  = (const float*)d_in[11];
  float* out = (float*)d_out;

  // workspace layout (floats); staged offset kept even for 8B alignment
  float* ws = (float*)d_ws;
  size_t o = 0;
  float* sums   = ws + o; o += (size_t)Ng * CD;   // |sums|cnts|gcur| zeroed in k_pre
  float* cnts   = ws + o; o += Ng;
  int*   gcur   = (int*)(ws + o); o += NBIN + 2;  // 784
  float* dinv   = ws + o; o += Nn;
  float* EW1    = ws + o; o += FIN * HD + 16;     // 464
  int*   startp = (int*)(ws + o); o += Nn + 16;
  unsigned short* degw = (unsigned short*)(ws + o); o += Nn / 2;
  unsigned char* argb  = (unsigned char*)(ws + o); o += Nn / 4 + 16;
  unsigned long long* staged = (unsigned long long*)(ws + o);
  o += (size_t)NBIN * CAPB * 2;
  unsigned* csr = (unsigned*)(ws + o); o += (size_t)NBIN * CAPB;
  unsigned char* hws1 = (unsigned char*)(ws + o); o += (size_t)Nn * HD / 4;  // fp8
  unsigned char* hws2 = (unsigned char*)(ws + o); o += (size_t)Nn * HD / 4;  // fp8
  __half* hw3s  = (__half*)(ws + o); o += (size_t)Nn * CD / 2;
  (void)ws_size; (void)n_in; (void)in_sizes; (void)out_size;

  int nzero = Ng * (CD + 1) + NBIN + 2;   // sums+cnts+gcur contiguous

  // pre: argmax + EW1 + zero | one-pass place | fine sort + embed
  k_pre<<<NBIN + 2, 256, 0, stream>>>(x, argb, emb, W1, EW1, sums, nzero);
  k_place1<<<NBLK, 256, 0, stream>>>(row, col, ea, gcur, staged);
  k_fine2<<<NBIN, 256, 0, stream>>>(gcur, staged, argb, EW1, csr, startp, degw, dinv, hws1);

  // wave-per-node convs; batched independent gathers
  k_conv<16><<<nblocks((long long)Nn * 64), 256, 0, stream>>>(
      startp, degw, csr, (const unsigned short*)hws1, dinv, b1, W2, hws2);
  k_conv<2><<<nblocks((long long)Nn * 64), 256, 0, stream>>>(
      startp, degw, csr, (const unsigned short*)hws2, dinv, b2, W3, hw3s);

  k_conv3pool<<<nblocks((long long)Nn * 8), 256, 0, stream>>>(
      startp, degw, csr, hw3s, dinv, b3, bat, sums, cnts);

  k_softmax<<<nblocks(Ng), 256, 0, stream>>>(sums, cnts, out, Ng);
}